// Round 1
// baseline (10885.570 us; speedup 1.0000x reference)
//
#include <hip/hip_runtime.h>
#include <hip/hip_bf16.h>
#include <stdint.h>

typedef __attribute__((ext_vector_type(8))) short short8;
typedef __attribute__((ext_vector_type(4))) float floatx4;
typedef __attribute__((ext_vector_type(4))) int intx4;
typedef __attribute__((ext_vector_type(2))) unsigned long long ull2;
typedef __attribute__((ext_vector_type(4))) unsigned short ushort4v;

#define DEVI __device__ __forceinline__

// ---- problem sizes ----
constexpr int B_ = 256, T_ = 512, D_ = 128, H_ = 512, C_ = 10;
constexpr int KTOT = H_ + D_;       // 640: k = [h(512) ; x(128)]
constexpr int RG = 16;              // batch rows per group
constexpr int NBG = 16;             // batch groups
constexpr int NCG = 16;             // column groups
constexpr int HCW = 32;             // h-cols per WG

// ---- workspace layout (bytes) ----
constexpr size_t OFF_XB = 0;
constexpr size_t SZ_XB  = (size_t)B_ * T_ * D_ * 2;          // x in bf16
constexpr size_t OFF_WC = OFF_XB + SZ_XB;
constexpr size_t SZ_WC  = (size_t)4 * H_ * KTOT * 2;         // Wcomb[4*H][640] bf16 (transposed)
constexpr size_t OFF_HB = OFF_WC + SZ_WC;
constexpr size_t SZ_HB  = (size_t)2 * B_ * H_ * 2;           // h double buffer bf16
constexpr size_t OFF_CT = OFF_HB + SZ_HB;
constexpr size_t SZ_CT  = (size_t)NBG * (T_ + 1) * 4;        // sync counters
constexpr size_t WS_NEED = OFF_CT + SZ_CT;

DEVI uint16_t f2bf(float f) {
    uint32_t u = __builtin_bit_cast(uint32_t, f);
    u += 0x7FFFu + ((u >> 16) & 1u);
    return (uint16_t)(u >> 16);
}
DEVI float bf2f(uint16_t u) {
    return __builtin_bit_cast(float, (uint32_t)u << 16);
}
DEVI float sigf(float x)  { return 1.0f / (1.0f + __expf(-x)); }
DEVI float tanhf_(float x){ return 1.0f - 2.0f / (1.0f + __expf(2.0f * x)); }

// ---- prep: x fp32 -> bf16 ----
__global__ void k_cvt_x(const float* __restrict__ x, uint16_t* __restrict__ xb) {
    int i = (blockIdx.x * 256 + threadIdx.x) * 4;   // total B*T*D = 16777216
    float4 v = *reinterpret_cast<const float4*>(x + i);
    ushort4v o;
    o.x = f2bf(v.x); o.y = f2bf(v.y); o.z = f2bf(v.z); o.w = f2bf(v.w);
    *reinterpret_cast<ushort4v*>(xb + i) = o;
}

// ---- prep: build combined transposed bf16 weights Wcomb[n'=g*512+n][k] ----
//  k<512 : W?h[k][n] ;  k>=512 : W?x[k-512][n]
__global__ void k_build_w(const float* __restrict__ wgh, const float* __restrict__ wih,
                          const float* __restrict__ wfh, const float* __restrict__ woh,
                          const float* __restrict__ wgx, const float* __restrict__ wix,
                          const float* __restrict__ wfx, const float* __restrict__ wox,
                          uint16_t* __restrict__ wc) {
    int np = blockIdx.x;            // 0..2047
    int g = np >> 9, n = np & 511;
    const float* wh = (g == 0) ? wgh : (g == 1) ? wih : (g == 2) ? wfh : woh;
    const float* wx = (g == 0) ? wgx : (g == 1) ? wix : (g == 2) ? wfx : wox;
    for (int k = threadIdx.x; k < KTOT; k += 256) {
        float v = (k < H_) ? wh[(size_t)k * H_ + n] : wx[(size_t)(k - H_) * H_ + n];
        wc[(size_t)np * KTOT + k] = f2bf(v);
    }
}

// ---- main recurrent kernel ----
__global__ __launch_bounds__(256, 1) void k_lstm(
    const uint16_t* __restrict__ xb,   // [B][T][D] bf16
    const uint16_t* __restrict__ wc,   // [4H][KTOT] bf16
    const float* __restrict__ bgp, const float* __restrict__ bip,
    const float* __restrict__ bfp, const float* __restrict__ bop,
    uint16_t* hbuf,                    // [2][B][H] bf16
    int* counters)                     // [NBG][T+1]
{
    __shared__ __align__(16) short hx[RG * KTOT];                 // 20 KB, XOR-swizzled
    __shared__ float pre[4][RG][HCW + 1];                         // 8448 B

    const int tid  = threadIdx.x;
    const int lane = tid & 63;
    const int w    = tid >> 6;          // wave id == gate id (g,i,f,o)
    const int bid  = blockIdx.x;
    // keep each batch-group's 16 WGs on one XCD (perf heuristic only)
    const int xcd = bid & 7, j = bid >> 3;
    const int bg = xcd * 2 + (j >> 4);
    const int cg = j & 15;
    const int b0  = bg * RG;
    const int hc0 = cg * HCW;

    // ---- load this wave's weight slice into registers (stays for all 512 steps) ----
    short8 bfr[2][20];
    {
        const int lcol = lane & 15, kgrp = lane >> 4;
        #pragma unroll
        for (int t2 = 0; t2 < 2; ++t2) {
            const uint16_t* src = wc + (size_t)(w * H_ + hc0 + t2 * 16 + lcol) * KTOT + kgrp * 8;
            #pragma unroll
            for (int ks = 0; ks < 20; ++ks)
                bfr[t2][ks] = *reinterpret_cast<const short8*>(src + ks * 32);
        }
    }

    // ---- elementwise thread mapping: (row, col pair) fixed for whole run ----
    const int erow = tid >> 4;          // 0..15
    const int ep   = tid & 15;          // 0..15 -> cols ep*2, ep*2+1
    const int hcg0 = hc0 + ep * 2;
    float bge[2], bie[2], bfe[2], boe[2], cst[2] = {0.f, 0.f};
    #pragma unroll
    for (int e = 0; e < 2; ++e) {
        bge[e] = bgp[hcg0 + e]; bie[e] = bip[hcg0 + e];
        bfe[e] = bfp[hcg0 + e]; boe[e] = bop[hcg0 + e];
    }

    // staging mapping: thread -> (row, 64B segment)
    const int srow = tid >> 4, sseg = tid & 15;
    const int sswz = (srow & 7) << 4;
    // A-fragment base (mfma 16x16x32: row = lane&15, k = (lane>>4)*8 + j)
    const int arow = lane & 15, akg = lane >> 4;
    const int abase = arow * (KTOT * 2) + akg * 16;
    const int aswz  = (arow & 7) << 4;

    int* ctr = counters + bg * (T_ + 1);
    char* lds = (char*)hx;

    for (int t = 0; t < T_; ++t) {
        // ---- wait for h_t from all 16 column groups ----
        if (t > 0) {
            if (tid == 0) {
                int it = 0;
                while (__hip_atomic_load(ctr + t, __ATOMIC_ACQUIRE, __HIP_MEMORY_SCOPE_AGENT) < NCG) {
                    if (++it > (1 << 28)) break;   // safety: fail loud, not hang
                    __builtin_amdgcn_s_sleep(1);
                }
            }
            __syncthreads();
        }

        // ---- stage A = [h_t ; x_t] into swizzled LDS ----
        if (t == 0) {
            intx4 z = {0, 0, 0, 0};
            #pragma unroll
            for (int c4 = 0; c4 < 4; ++c4) {
                int byte = srow * (KTOT * 2) + sseg * 64 + c4 * 16;
                *reinterpret_cast<intx4*>(lds + (byte ^ sswz)) = z;
            }
        } else {
            const unsigned long long* src = reinterpret_cast<const unsigned long long*>(
                hbuf + (size_t)(t & 1) * B_ * H_ + (size_t)(b0 + srow) * H_ + sseg * 32);
            #pragma unroll
            for (int c4 = 0; c4 < 4; ++c4) {
                unsigned long long lo = __hip_atomic_load(src + c4 * 2,     __ATOMIC_RELAXED, __HIP_MEMORY_SCOPE_AGENT);
                unsigned long long hi = __hip_atomic_load(src + c4 * 2 + 1, __ATOMIC_RELAXED, __HIP_MEMORY_SCOPE_AGENT);
                ull2 v; v.x = lo; v.y = hi;
                int byte = srow * (KTOT * 2) + sseg * 64 + c4 * 16;
                *reinterpret_cast<ull2*>(lds + (byte ^ sswz)) = v;
            }
        }
        {   // x part: cols 512..639
            const short8 xv = *reinterpret_cast<const short8*>(
                xb + ((size_t)(b0 + srow) * T_ + t) * D_ + sseg * 8);
            int byte = srow * (KTOT * 2) + H_ * 2 + sseg * 16;
            *reinterpret_cast<short8*>(lds + (byte ^ sswz)) = xv;
        }
        __syncthreads();

        // ---- MFMA: preact[16 x 32] for gate w, K = 640 ----
        floatx4 acc0 = {0.f, 0.f, 0.f, 0.f}, acc1 = {0.f, 0.f, 0.f, 0.f};
        #pragma unroll
        for (int ks = 0; ks < 20; ++ks) {
            int byte = (abase + ks * 64) ^ aswz;
            short8 a = *reinterpret_cast<const short8*>(lds + byte);
            acc0 = __builtin_amdgcn_mfma_f32_16x16x32_bf16(a, bfr[0][ks], acc0, 0, 0, 0);
            acc1 = __builtin_amdgcn_mfma_f32_16x16x32_bf16(a, bfr[1][ks], acc1, 0, 0, 0);
        }
        // C layout: col = lane&15, row = (lane>>4)*4 + r  (m89-verified)
        #pragma unroll
        for (int r = 0; r < 4; ++r) {
            pre[w][(lane >> 4) * 4 + r][(lane & 15)]      = acc0[r];
            pre[w][(lane >> 4) * 4 + r][16 + (lane & 15)] = acc1[r];
        }
        __syncthreads();

        // ---- elementwise LSTM cell; c-state lives in regs ----
        float hp[2];
        #pragma unroll
        for (int e = 0; e < 2; ++e) {
            int col = ep * 2 + e;
            float ag = pre[0][erow][col] + bge[e];
            float ai = pre[1][erow][col] + bie[e];
            float af = pre[2][erow][col] + bfe[e];
            float ao = pre[3][erow][col] + boe[e];
            float g = tanhf_(ag), ii = sigf(ai), f = sigf(af), o = sigf(ao);
            float c = g * ii + cst[e] * f;
            cst[e] = c;
            hp[e] = tanhf_(c) * o;
        }
        uint32_t packed = (uint32_t)f2bf(hp[0]) | ((uint32_t)f2bf(hp[1]) << 16);
        uint32_t* hdst = reinterpret_cast<uint32_t*>(
            hbuf + (size_t)((t + 1) & 1) * B_ * H_ + (size_t)(b0 + erow) * H_ + hcg0);
        __hip_atomic_store(hdst, packed, __ATOMIC_RELAXED, __HIP_MEMORY_SCOPE_AGENT);
        __threadfence();
        __syncthreads();
        if (tid == 0)
            __hip_atomic_fetch_add(ctr + t + 1, 1, __ATOMIC_RELEASE, __HIP_MEMORY_SCOPE_AGENT);
        // next iteration's t>0 wait-barrier protects hx from early overwrite
    }
}

// ---- final projection: out[b][c] = h_T[b] . wph[:,c] + bp[c] ----
__global__ void k_proj(const uint16_t* __restrict__ hb0, const float* __restrict__ wph,
                       const float* __restrict__ bp, float* __restrict__ out) {
    int b = blockIdx.x, lane = threadIdx.x;     // 64 threads
    float p[C_];
    #pragma unroll
    for (int c = 0; c < C_; ++c) p[c] = 0.f;
    for (int k = lane; k < H_; k += 64) {
        float hv = bf2f(hb0[(size_t)b * H_ + k]);
        #pragma unroll
        for (int c = 0; c < C_; ++c) p[c] += hv * wph[(size_t)k * C_ + c];
    }
    #pragma unroll
    for (int c = 0; c < C_; ++c) {
        float v = p[c];
        #pragma unroll
        for (int off = 32; off; off >>= 1) v += __shfl_down(v, off, 64);
        if (lane == 0) out[(size_t)b * C_ + c] = v + bp[c];
    }
}

extern "C" void kernel_launch(void* const* d_in, const int* in_sizes, int n_in,
                              void* d_out, int out_size, void* d_ws, size_t ws_size,
                              hipStream_t stream) {
    const float* x   = (const float*)d_in[0];
    const float* wgx = (const float*)d_in[1];
    const float* wgh = (const float*)d_in[2];
    const float* bg  = (const float*)d_in[3];
    const float* wix = (const float*)d_in[4];
    const float* wih = (const float*)d_in[5];
    const float* bi  = (const float*)d_in[6];
    const float* wfx = (const float*)d_in[7];
    const float* wfh = (const float*)d_in[8];
    const float* bf  = (const float*)d_in[9];
    const float* wox = (const float*)d_in[10];
    const float* woh = (const float*)d_in[11];
    const float* bo  = (const float*)d_in[12];
    const float* wph = (const float*)d_in[13];
    const float* bp  = (const float*)d_in[14];

    if (ws_size < WS_NEED) return;  // fail loud (wrong output) rather than corrupt

    char* ws = (char*)d_ws;
    uint16_t* xbp = (uint16_t*)(ws + OFF_XB);
    uint16_t* wcp = (uint16_t*)(ws + OFF_WC);
    uint16_t* hbp = (uint16_t*)(ws + OFF_HB);
    int*      ctp = (int*)(ws + OFF_CT);

    hipMemsetAsync(ctp, 0, SZ_CT, stream);
    k_cvt_x<<<(B_ * T_ * D_) / (256 * 4), 256, 0, stream>>>(x, xbp);
    k_build_w<<<4 * H_, 256, 0, stream>>>(wgh, wih, wfh, woh, wgx, wix, wfx, wox, wcp);
    k_lstm<<<256, 256, 0, stream>>>(xbp, wcp, bg, bi, bf, bo, hbp, ctp);
    k_proj<<<B_, 64, 0, stream>>>(hbp /* parity 0 holds h_T */, wph, bp, (float*)d_out);
}

// Round 2
// 1604.210 us; speedup vs baseline: 6.7856x; 6.7856x over previous
//
#include <hip/hip_runtime.h>
#include <hip/hip_bf16.h>
#include <stdint.h>

typedef __attribute__((ext_vector_type(8))) short short8;
typedef __attribute__((ext_vector_type(4))) float floatx4;
typedef __attribute__((ext_vector_type(4))) int intx4;
typedef __attribute__((ext_vector_type(2))) unsigned long long ull2;
typedef __attribute__((ext_vector_type(4))) unsigned short ushort4v;

#define DEVI __device__ __forceinline__

// ---- problem sizes ----
constexpr int B_ = 256, T_ = 512, D_ = 128, H_ = 512, C_ = 10;
constexpr int KTOT = H_ + D_;       // 640: k = [h(512) ; x(128)]
constexpr int RG = 16;              // batch rows per group
constexpr int NBG = 16;             // batch groups
constexpr int NCG = 16;             // column groups
constexpr int HCW = 32;             // h-cols per WG

// ---- workspace layout (bytes) ----
constexpr size_t OFF_XB = 0;
constexpr size_t SZ_XB  = (size_t)B_ * T_ * D_ * 2;          // x in bf16
constexpr size_t OFF_WC = OFF_XB + SZ_XB;
constexpr size_t SZ_WC  = (size_t)4 * H_ * KTOT * 2;         // Wcomb[4*H][640] bf16 (transposed)
constexpr size_t OFF_HB = OFF_WC + SZ_WC;
constexpr size_t SZ_HB  = (size_t)2 * B_ * H_ * 2;           // h double buffer bf16
constexpr size_t OFF_CT = OFF_HB + SZ_HB;
constexpr size_t SZ_CT  = (size_t)NBG * (T_ + 1) * 4;        // sync counters
constexpr size_t WS_NEED = OFF_CT + SZ_CT;

DEVI uint16_t f2bf(float f) {
    uint32_t u = __builtin_bit_cast(uint32_t, f);
    u += 0x7FFFu + ((u >> 16) & 1u);
    return (uint16_t)(u >> 16);
}
DEVI float bf2f(uint16_t u) {
    return __builtin_bit_cast(float, (uint32_t)u << 16);
}
DEVI float sigf(float x)  { return 1.0f / (1.0f + __expf(-x)); }
DEVI float tanhf_(float x){ return 1.0f - 2.0f / (1.0f + __expf(2.0f * x)); }

// ---- prep: x fp32 -> bf16 ----
__global__ void k_cvt_x(const float* __restrict__ x, uint16_t* __restrict__ xb) {
    int i = (blockIdx.x * 256 + threadIdx.x) * 4;   // total B*T*D = 16777216
    float4 v = *reinterpret_cast<const float4*>(x + i);
    ushort4v o;
    o.x = f2bf(v.x); o.y = f2bf(v.y); o.z = f2bf(v.z); o.w = f2bf(v.w);
    *reinterpret_cast<ushort4v*>(xb + i) = o;
}

// ---- prep: build combined transposed bf16 weights Wcomb[n'=g*512+n][k] ----
//  k<512 : W?h[k][n] ;  k>=512 : W?x[k-512][n]
__global__ void k_build_w(const float* __restrict__ wgh, const float* __restrict__ wih,
                          const float* __restrict__ wfh, const float* __restrict__ woh,
                          const float* __restrict__ wgx, const float* __restrict__ wix,
                          const float* __restrict__ wfx, const float* __restrict__ wox,
                          uint16_t* __restrict__ wc) {
    int np = blockIdx.x;            // 0..2047
    int g = np >> 9, n = np & 511;
    const float* wh = (g == 0) ? wgh : (g == 1) ? wih : (g == 2) ? wfh : woh;
    const float* wx = (g == 0) ? wgx : (g == 1) ? wix : (g == 2) ? wfx : wox;
    for (int k = threadIdx.x; k < KTOT; k += 256) {
        float v = (k < H_) ? wh[(size_t)k * H_ + n] : wx[(size_t)(k - H_) * H_ + n];
        wc[(size_t)np * KTOT + k] = f2bf(v);
    }
}

// ---- main recurrent kernel ----
__global__ __launch_bounds__(256, 1) void k_lstm(
    const uint16_t* __restrict__ xb,   // [B][T][D] bf16
    const uint16_t* __restrict__ wc,   // [4H][KTOT] bf16
    const float* __restrict__ bgp, const float* __restrict__ bip,
    const float* __restrict__ bfp, const float* __restrict__ bop,
    uint16_t* hbuf,                    // [2][B][H] bf16
    int* counters)                     // [NBG][T+1]
{
    __shared__ __align__(16) short hx[RG * KTOT];                 // 20 KB, XOR-swizzled
    __shared__ float pre[4][RG][HCW + 1];                         // 8448 B

    const int tid  = threadIdx.x;
    const int lane = tid & 63;
    const int w    = tid >> 6;          // wave id == gate id (g,i,f,o)
    const int bid  = blockIdx.x;
    // keep each batch-group's 16 WGs on one XCD (perf heuristic only)
    const int xcd = bid & 7, j = bid >> 3;
    const int bg = xcd * 2 + (j >> 4);
    const int cg = j & 15;
    const int b0  = bg * RG;
    const int hc0 = cg * HCW;

    // ---- load this wave's weight slice into registers (stays for all 512 steps) ----
    short8 bfr[2][20];
    {
        const int lcol = lane & 15, kgrp = lane >> 4;
        #pragma unroll
        for (int t2 = 0; t2 < 2; ++t2) {
            const uint16_t* src = wc + (size_t)(w * H_ + hc0 + t2 * 16 + lcol) * KTOT + kgrp * 8;
            #pragma unroll
            for (int ks = 0; ks < 20; ++ks)
                bfr[t2][ks] = *reinterpret_cast<const short8*>(src + ks * 32);
        }
    }

    // ---- elementwise thread mapping: (row, col pair) fixed for whole run ----
    const int erow = tid >> 4;          // 0..15
    const int ep   = tid & 15;          // 0..15 -> cols ep*2, ep*2+1
    const int hcg0 = hc0 + ep * 2;
    float bge[2], bie[2], bfe[2], boe[2], cst[2] = {0.f, 0.f};
    #pragma unroll
    for (int e = 0; e < 2; ++e) {
        bge[e] = bgp[hcg0 + e]; bie[e] = bip[hcg0 + e];
        bfe[e] = bfp[hcg0 + e]; boe[e] = bop[hcg0 + e];
    }

    // staging mapping: thread -> (row, 64B segment)
    const int srow = tid >> 4, sseg = tid & 15;
    const int sswz = (srow & 7) << 4;
    // A-fragment base (mfma 16x16x32: row = lane&15, k = (lane>>4)*8 + j)
    const int arow = lane & 15, akg = lane >> 4;
    const int abase = arow * (KTOT * 2) + akg * 16;
    const int aswz  = (arow & 7) << 4;

    int* ctr = counters + bg * (T_ + 1);
    char* lds = (char*)hx;

    for (int t = 0; t < T_; ++t) {
        // ---- stage x part (cols 512..639) BEFORE the wait: does not depend on h_t,
        //      and previous step's MFMA reads of hx finished at the pre-write barrier ----
        {
            const short8 xv = *reinterpret_cast<const short8*>(
                xb + ((size_t)(b0 + srow) * T_ + t) * D_ + sseg * 8);
            int byte = srow * (KTOT * 2) + H_ * 2 + sseg * 16;
            *reinterpret_cast<short8*>(lds + (byte ^ sswz)) = xv;
        }

        // ---- wait for h_t from all 16 column groups (RELAXED poll: no L2 invalidates;
        //      the h loads below bypass L2 (sc1) so no cache maintenance is needed) ----
        if (t > 0) {
            if (tid == 0) {
                int it = 0;
                while (__hip_atomic_load(ctr + t, __ATOMIC_RELAXED, __HIP_MEMORY_SCOPE_AGENT) < NCG) {
                    if (++it > (1 << 28)) break;   // safety: fail loud, not hang
                    __builtin_amdgcn_s_sleep(1);
                }
                asm volatile("" ::: "memory");     // compiler reordering fence only
            }
            __syncthreads();
        }

        // ---- stage A = [h_t ; x_t] into swizzled LDS ----
        if (t == 0) {
            intx4 z = {0, 0, 0, 0};
            #pragma unroll
            for (int c4 = 0; c4 < 4; ++c4) {
                int byte = srow * (KTOT * 2) + sseg * 64 + c4 * 16;
                *reinterpret_cast<intx4*>(lds + (byte ^ sswz)) = z;
            }
        } else {
            const unsigned long long* src = reinterpret_cast<const unsigned long long*>(
                hbuf + (size_t)(t & 1) * B_ * H_ + (size_t)(b0 + srow) * H_ + sseg * 32);
            #pragma unroll
            for (int c4 = 0; c4 < 4; ++c4) {
                unsigned long long lo = __hip_atomic_load(src + c4 * 2,     __ATOMIC_RELAXED, __HIP_MEMORY_SCOPE_AGENT);
                unsigned long long hi = __hip_atomic_load(src + c4 * 2 + 1, __ATOMIC_RELAXED, __HIP_MEMORY_SCOPE_AGENT);
                ull2 v; v.x = lo; v.y = hi;
                int byte = srow * (KTOT * 2) + sseg * 64 + c4 * 16;
                *reinterpret_cast<ull2*>(lds + (byte ^ sswz)) = v;
            }
        }
        __syncthreads();

        // ---- MFMA: preact[16 x 32] for gate w, K = 640 ----
        floatx4 acc0 = {0.f, 0.f, 0.f, 0.f}, acc1 = {0.f, 0.f, 0.f, 0.f};
        #pragma unroll
        for (int ks = 0; ks < 20; ++ks) {
            int byte = (abase + ks * 64) ^ aswz;
            short8 a = *reinterpret_cast<const short8*>(lds + byte);
            acc0 = __builtin_amdgcn_mfma_f32_16x16x32_bf16(a, bfr[0][ks], acc0, 0, 0, 0);
            acc1 = __builtin_amdgcn_mfma_f32_16x16x32_bf16(a, bfr[1][ks], acc1, 0, 0, 0);
        }
        // C layout: col = lane&15, row = (lane>>4)*4 + r  (m89-verified)
        #pragma unroll
        for (int r = 0; r < 4; ++r) {
            pre[w][(lane >> 4) * 4 + r][(lane & 15)]      = acc0[r];
            pre[w][(lane >> 4) * 4 + r][16 + (lane & 15)] = acc1[r];
        }
        __syncthreads();

        // ---- elementwise LSTM cell; c-state lives in regs ----
        float hp[2];
        #pragma unroll
        for (int e = 0; e < 2; ++e) {
            int col = ep * 2 + e;
            float ag = pre[0][erow][col] + bge[e];
            float ai = pre[1][erow][col] + bie[e];
            float af = pre[2][erow][col] + bfe[e];
            float ao = pre[3][erow][col] + boe[e];
            float g = tanhf_(ag), ii = sigf(ai), f = sigf(af), o = sigf(ao);
            float c = g * ii + cst[e] * f;
            cst[e] = c;
            hp[e] = tanhf_(c) * o;
        }
        uint32_t packed = (uint32_t)f2bf(hp[0]) | ((uint32_t)f2bf(hp[1]) << 16);
        uint32_t* hdst = reinterpret_cast<uint32_t*>(
            hbuf + (size_t)((t + 1) & 1) * B_ * H_ + (size_t)(b0 + erow) * H_ + hcg0);
        __hip_atomic_store(hdst, packed, __ATOMIC_RELAXED, __HIP_MEMORY_SCOPE_AGENT);
        // stores are sc1 write-through: vmcnt(0) == visible at device coherence point.
        // NO __threadfence() (that emits a full-L2 writeback on gfx950).
        asm volatile("s_waitcnt vmcnt(0)" ::: "memory");
        __syncthreads();   // all threads past their waitcnt -> all h stores visible
        if (tid == 0)
            __hip_atomic_fetch_add(ctr + t + 1, 1, __ATOMIC_RELAXED, __HIP_MEMORY_SCOPE_AGENT);
        // next iteration's t>0 wait-barrier protects hx from early overwrite
    }
}

// ---- final projection: out[b][c] = h_T[b] . wph[:,c] + bp[c] ----
// hbuf was written with cache-bypassing (sc1) stores; read it the same way so a
// stale L2 line on a different XCD can never be observed.
__global__ void k_proj(const uint16_t* __restrict__ hb0, const float* __restrict__ wph,
                       const float* __restrict__ bp, float* __restrict__ out) {
    int b = blockIdx.x, lane = threadIdx.x;     // 64 threads
    const uint32_t* hrow = reinterpret_cast<const uint32_t*>(hb0 + (size_t)b * H_);
    float p[C_];
    #pragma unroll
    for (int c = 0; c < C_; ++c) p[c] = 0.f;
    #pragma unroll
    for (int q = 0; q < 4; ++q) {
        int k2 = lane + q * 64;                 // uint32 index 0..255 -> elems 2k2, 2k2+1
        uint32_t u = __hip_atomic_load(hrow + k2, __ATOMIC_RELAXED, __HIP_MEMORY_SCOPE_AGENT);
        float h0 = bf2f((uint16_t)(u & 0xFFFFu));
        float h1 = bf2f((uint16_t)(u >> 16));
        #pragma unroll
        for (int c = 0; c < C_; ++c)
            p[c] += h0 * wph[(size_t)(2 * k2) * C_ + c] + h1 * wph[(size_t)(2 * k2 + 1) * C_ + c];
    }
    #pragma unroll
    for (int c = 0; c < C_; ++c) {
        float v = p[c];
        #pragma unroll
        for (int off = 32; off; off >>= 1) v += __shfl_down(v, off, 64);
        if (lane == 0) out[(size_t)b * C_ + c] = v + bp[c];
    }
}

extern "C" void kernel_launch(void* const* d_in, const int* in_sizes, int n_in,
                              void* d_out, int out_size, void* d_ws, size_t ws_size,
                              hipStream_t stream) {
    const float* x   = (const float*)d_in[0];
    const float* wgx = (const float*)d_in[1];
    const float* wgh = (const float*)d_in[2];
    const float* bg  = (const float*)d_in[3];
    const float* wix = (const float*)d_in[4];
    const float* wih = (const float*)d_in[5];
    const float* bi  = (const float*)d_in[6];
    const float* wfx = (const float*)d_in[7];
    const float* wfh = (const float*)d_in[8];
    const float* bf  = (const float*)d_in[9];
    const float* wox = (const float*)d_in[10];
    const float* woh = (const float*)d_in[11];
    const float* bo  = (const float*)d_in[12];
    const float* wph = (const float*)d_in[13];
    const float* bp  = (const float*)d_in[14];

    if (ws_size < WS_NEED) return;  // fail loud (wrong output) rather than corrupt

    char* ws = (char*)d_ws;
    uint16_t* xbp = (uint16_t*)(ws + OFF_XB);
    uint16_t* wcp = (uint16_t*)(ws + OFF_WC);
    uint16_t* hbp = (uint16_t*)(ws + OFF_HB);
    int*      ctp = (int*)(ws + OFF_CT);

    hipMemsetAsync(ctp, 0, SZ_CT, stream);
    k_cvt_x<<<(B_ * T_ * D_) / (256 * 4), 256, 0, stream>>>(x, xbp);
    k_build_w<<<4 * H_, 256, 0, stream>>>(wgh, wih, wfh, woh, wgx, wix, wfx, wox, wcp);
    k_lstm<<<256, 256, 0, stream>>>(xbp, wcp, bg, bi, bf, bo, hbp, ctp);
    k_proj<<<B_, 64, 0, stream>>>(hbp /* parity 0 holds h_T */, wph, bp, (float*)d_out);
}